// Round 8
// baseline (128.653 us; speedup 1.0000x reference)
//
#include <hip/hip_runtime.h>
#include <stdint.h>

#define NW   2048
#define OBS  512
#define HS   512
#define HS2  512
#define HM   256
#define CTX  128
#define ACT  18

#define K2LE 2.8853900817779268f   // 2*log2(e)

// ws layout (floats)
#define W1T_OFF   0          // [512][512] k-major
#define WCT_OFF   262144     // [256][128]
#define WHHT_OFF  294912     // [256][768]
#define W2T_OFF   491520     // [768][512]
#define FEAT_OFF  884736     // [2048][512]
#define HTERM_OFF 1933312    // [2048][128]  (pre-scaled by 2*log2e)
#define GATES_OFF 2195456    // [2048][768]; aliased as OUT2 [2048][512] after attn
#define OUT2_OFF  2195456
#define HNEW_OFF  3768320    // [2048][256]
// total 4,292,608 floats = 17.2 MB

#if __has_builtin(__builtin_amdgcn_exp2f)
#define EXP2F(x) __builtin_amdgcn_exp2f(x)
#else
#define EXP2F(x) exp2f(x)
#endif
#if __has_builtin(__builtin_amdgcn_rcpf)
#define RCPF(x) __builtin_amdgcn_rcpf(x)
#else
#define RCPF(x) (1.0f/(x))
#endif

// ---------------- threefry2x32 (key = (0,42)), 20 rounds ----------------
#define TFR(x0, x1, R) { x0 += x1; x1 = (x1 << R) | (x1 >> (32 - R)); x1 ^= x0; }

__device__ __forceinline__ void threefry_0_42(uint32_t x0, uint32_t x1,
                                              uint32_t& o0, uint32_t& o1) {
    const uint32_t ks0 = 0u;
    const uint32_t ks1 = 42u;
    const uint32_t ks2 = 0x1BD11BDAu ^ ks0 ^ ks1;
    x0 += ks0; x1 += ks1;
    TFR(x0, x1, 13) TFR(x0, x1, 15) TFR(x0, x1, 26) TFR(x0, x1, 6)
    x0 += ks1; x1 += ks2 + 1u;
    TFR(x0, x1, 17) TFR(x0, x1, 29) TFR(x0, x1, 16) TFR(x0, x1, 24)
    x0 += ks2; x1 += ks0 + 2u;
    TFR(x0, x1, 13) TFR(x0, x1, 15) TFR(x0, x1, 26) TFR(x0, x1, 6)
    x0 += ks0; x1 += ks1 + 3u;
    TFR(x0, x1, 17) TFR(x0, x1, 29) TFR(x0, x1, 16) TFR(x0, x1, 24)
    x0 += ks1; x1 += ks2 + 4u;
    TFR(x0, x1, 13) TFR(x0, x1, 15) TFR(x0, x1, 26) TFR(x0, x1, 6)
    x0 += ks2; x1 += ks0 + 5u;
    o0 = x0; o1 = x1;
}

// jax_threefry_partitionable scheme (verified round 2): counter=(0,n), out0^out1
__device__ __forceinline__ float gumbel_ra(int row, int a) {
    uint32_t n = (uint32_t)(row * ACT + a);
    uint32_t o0, o1;
    threefry_0_42(0u, n, o0, o1);
    uint32_t bits = o0 ^ o1;
    uint32_t fb = (bits >> 9) | 0x3F800000u;
    float f = __uint_as_float(fb) - 1.0f;
    const float tiny = 1.17549435e-38f;
    float u = (f < tiny) ? tiny : f;
    return -logf(-logf(u));
}

__device__ __forceinline__ float fast_tanh(float x) {
    float e = __expf(2.0f * x);
    return 1.0f - 2.0f / (e + 1.0f);
}
__device__ __forceinline__ float fast_sig(float x) {
    return 1.0f / (1.0f + __expf(-x));
}
__device__ __forceinline__ void fma4(float4& a, float s, const float4 w) {
    a.x = fmaf(s, w.x, a.x); a.y = fmaf(s, w.y, a.y);
    a.z = fmaf(s, w.z, a.z); a.w = fmaf(s, w.w, a.w);
}

// ---- weight prep: 32x32 LDS-tiled transposes into ws (round-4 version) ----
__global__ __launch_bounds__(256) void transpose_weights(
    const float* __restrict__ W1, const float* __restrict__ Wc,
    const float* __restrict__ Whh, const float* __restrict__ W2,
    float* __restrict__ ws)
{
    int b = blockIdx.x;
    const float* src; float* dst; int ld, off, R, it, jt;
    if (b < 256)      { src = W1;  dst = ws + W1T_OFF;  ld = 512; off = 0; it = b >> 4; jt = b & 15; R = 512; }
    else if (b < 288) { b -= 256; src = Wc;  dst = ws + WCT_OFF;  ld = 257; off = 1; it = b >> 3; jt = b & 7;  R = 128; }
    else if (b < 480) { b -= 288; src = Whh; dst = ws + WHHT_OFF; ld = 256; off = 0; it = b / 8;  jt = b % 8;  R = 768; }
    else              { b -= 480; src = W2;  dst = ws + W2T_OFF;  ld = 768; off = 0; it = b / 24; jt = b % 24; R = 512; }
    __shared__ float t[32][33];
    const int tx = threadIdx.x & 31, ty = threadIdx.x >> 5;   // 32 x 8
    const int i0 = it * 32, j0 = jt * 32;
    #pragma unroll
    for (int q = 0; q < 4; ++q)
        t[ty + 8 * q][tx] = src[(i0 + ty + 8 * q) * ld + off + j0 + tx];
    __syncthreads();
    #pragma unroll
    for (int q = 0; q < 4; ++q)
        dst[(j0 + ty + 8 * q) * R + i0 + tx] = t[tx][ty + 8 * q];
}

// ---- mega-GEMM: 16 rows x 128 cols per block, 8-way k-split ----
// jobs: [0,512): feat = relu(obs@W1T + b1)
//       [512,640): hterm = K2LE*(h@WcT + bc)
//       [640,1408): gates = h@WhhT + b_hh
__global__ __launch_bounds__(256) void gemm_bcast(
    const float* __restrict__ obs, const float* __restrict__ hmem,
    const float* __restrict__ b1,  const float* __restrict__ bc,
    const float* __restrict__ bhh, float* __restrict__ ws)
{
    __shared__ float s_act[16 * 768];          // 48 KB; P aliased below
    float4* P = (float4*)s_act;                // [16][4][32]

    int bid = blockIdx.x;
    const float* A; int lda; const float4* Bt4; int NQ, K, kshift;
    const float* bias; float* C; int ldc; float scale; int act; int rowb, colb;
    if (bid < 512) {
        rowb = bid >> 2; colb = bid & 3;
        A = obs; lda = 512; Bt4 = (const float4*)(ws + W1T_OFF); NQ = 128; K = 512; kshift = 7;
        bias = b1; C = ws + FEAT_OFF; ldc = 512; scale = 1.0f; act = 1;
    } else if (bid < 640) {
        rowb = bid - 512; colb = 0;
        A = hmem; lda = 256; Bt4 = (const float4*)(ws + WCT_OFF); NQ = 32; K = 256; kshift = 6;
        bias = bc; C = ws + HTERM_OFF; ldc = 128; scale = K2LE; act = 0;
    } else {
        int i = bid - 640; rowb = i / 6; colb = i - rowb * 6;
        A = hmem; lda = 256; Bt4 = (const float4*)(ws + WHHT_OFF); NQ = 192; K = 256; kshift = 6;
        bias = bhh; C = ws + GATES_OFF; ldc = 768; scale = 1.0f; act = 0;
    }
    const int m0 = rowb * 16;
    const int kq4 = K >> 2;

    // stage 16 A-rows into LDS (coalesced float4)
    for (int i = threadIdx.x; i < 16 * kq4; i += 256) {
        int r = i >> kshift, kq = i & (kq4 - 1);
        *(float4*)&s_act[r * K + kq * 4] =
            *(const float4*)&A[(size_t)(m0 + r) * lda + kq * 4];
    }
    __syncthreads();

    const int lane = threadIdx.x & 63, wv = threadIdx.x >> 6;
    const int kq2 = lane & 1, c4l = lane >> 1;
    const int kslice = K >> 3;
    const int k0 = (wv * 2 + kq2) * kslice;
    const int cq = colb * 32 + c4l;

    float4 acc[16];
    #pragma unroll
    for (int r = 0; r < 16; ++r) acc[r] = make_float4(0.f, 0.f, 0.f, 0.f);

    #pragma unroll 2
    for (int kk = k0; kk < k0 + kslice; kk += 4) {
        float4 w0 = Bt4[(kk + 0) * NQ + cq];
        float4 w1 = Bt4[(kk + 1) * NQ + cq];
        float4 w2 = Bt4[(kk + 2) * NQ + cq];
        float4 w3 = Bt4[(kk + 3) * NQ + cq];
        #pragma unroll
        for (int r = 0; r < 16; ++r) {
            float4 o = *(const float4*)&s_act[r * K + kk];  // 2-addr broadcast
            fma4(acc[r], o.x, w0); fma4(acc[r], o.y, w1);
            fma4(acc[r], o.z, w2); fma4(acc[r], o.w, w3);
        }
    }
    // in-wave k-pair reduce
    #pragma unroll
    for (int r = 0; r < 16; ++r) {
        acc[r].x += __shfl_xor(acc[r].x, 1);
        acc[r].y += __shfl_xor(acc[r].y, 1);
        acc[r].z += __shfl_xor(acc[r].z, 1);
        acc[r].w += __shfl_xor(acc[r].w, 1);
    }
    __syncthreads();            // all s_act reads done; alias P
    if (kq2 == 0) {
        #pragma unroll
        for (int r = 0; r < 16; ++r) P[(r * 4 + wv) * 32 + c4l] = acc[r];
    }
    __syncthreads();
    const float4* bias4 = (const float4*)bias;
    for (int s = threadIdx.x; s < 512; s += 256) {
        int r = s >> 5, c = s & 31;
        float4 p0 = P[(r * 4 + 0) * 32 + c];
        float4 p1 = P[(r * 4 + 1) * 32 + c];
        float4 p2 = P[(r * 4 + 2) * 32 + c];
        float4 p3 = P[(r * 4 + 3) * 32 + c];
        float4 bb = bias4[colb * 32 + c];
        float4 v;
        v.x = (p0.x + p1.x + p2.x + p3.x + bb.x) * scale;
        v.y = (p0.y + p1.y + p2.y + p3.y + bb.y) * scale;
        v.z = (p0.z + p1.z + p2.z + p3.z + bb.z) * scale;
        v.w = (p0.w + p1.w + p2.w + p3.w + bb.w) * scale;
        if (act) {
            v.x = fmaxf(v.x, 0.f); v.y = fmaxf(v.y, 0.f);
            v.z = fmaxf(v.z, 0.f); v.w = fmaxf(v.w, 0.f);
        }
        *(float4*)&C[(size_t)(m0 + r) * ldc + (colb * 32 + c) * 4] = v;
    }
}

// ---- attention (tanh ctx + softmax + dset) + GRU finish; 8 rows/block ----
__global__ __launch_bounds__(512) void attn_gru_kernel(
    const float* __restrict__ obs,  const float* __restrict__ hmem,
    const float* __restrict__ Wc,   const float* __restrict__ Wa,
    const float* __restrict__ ba,   const float* __restrict__ W_ih,
    const float* __restrict__ b_ih, float* __restrict__ ws)
{
    __shared__ float s_obs[8][512];    // 16 KB
    __shared__ float s_ht[8][128];     // 4 KB  (already K2LE-scaled)
    __shared__ float s_alog[8][512];   // 16 KB
    __shared__ float s_wc0[128], s_wa2[128];
    __shared__ float s_x[8];

    const int tid = threadIdx.x;
    const int row0 = blockIdx.x * 8;
    const float* hterm = ws + HTERM_OFF;
    const float* gates = ws + GATES_OFF;
    float* hnew = ws + HNEW_OFF;

    for (int i = tid; i < 1024; i += 512) {       // obs: 8 rows x 128 quads
        int r = i >> 7, kq = i & 127;
        *(float4*)&s_obs[r][kq * 4] =
            *(const float4*)&obs[(size_t)(row0 + r) * 512 + kq * 4];
    }
    if (tid < 256) {                              // hterm: 8 x 32 quads
        int r = tid >> 5, kq = tid & 31;
        *(float4*)&s_ht[r][kq * 4] =
            *(const float4*)&hterm[(size_t)(row0 + r) * 128 + kq * 4];
    }
    if (tid < 128) {
        s_wc0[tid] = K2LE * Wc[tid * (HM + 1)];
        s_wa2[tid] = 2.0f * Wa[tid];
    }
    __syncthreads();

    // alog[r][o] = ba + Swa - sum_c (2wa_c) / (1 + 2^(ob*wc0s + hts))
    {
        const float ba0 = ba[0];
        const int o = tid;
        float ob[8], acA[8];
        #pragma unroll
        for (int r = 0; r < 8; ++r) { ob[r] = s_obs[r][o]; acA[r] = 0.f; }
        float swa = 0.f;
        for (int c = 0; c < 128; c += 4) {
            float4 v = *(const float4*)&s_wa2[c];
            swa += v.x + v.y + v.z + v.w;
        }
        swa *= 0.5f;
        for (int c4 = 0; c4 < 32; ++c4) {
            float4 wc = *(const float4*)&s_wc0[c4 * 4];
            float4 wa = *(const float4*)&s_wa2[c4 * 4];
            #pragma unroll
            for (int r = 0; r < 8; ++r) {
                float4 ht = *(const float4*)&s_ht[r][c4 * 4];
                float t0 = fmaf(ob[r], wc.x, ht.x);
                acA[r] = fmaf(wa.x, RCPF(EXP2F(t0) + 1.f), acA[r]);
                float t1 = fmaf(ob[r], wc.y, ht.y);
                acA[r] = fmaf(wa.y, RCPF(EXP2F(t1) + 1.f), acA[r]);
                float t2 = fmaf(ob[r], wc.z, ht.z);
                acA[r] = fmaf(wa.z, RCPF(EXP2F(t2) + 1.f), acA[r]);
                float t3 = fmaf(ob[r], wc.w, ht.w);
                acA[r] = fmaf(wa.w, RCPF(EXP2F(t3) + 1.f), acA[r]);
            }
        }
        #pragma unroll
        for (int r = 0; r < 8; ++r) s_alog[r][o] = ba0 + swa - acA[r];
    }
    __syncthreads();

    // softmax + dset -> x[r]; wave per row (8 waves, 8 rows)
    {
        const int wv = tid >> 6, lane = tid & 63;
        const int r = wv;
        float m = -1e30f;
        for (int o = lane; o < 512; o += 64) m = fmaxf(m, s_alog[r][o]);
        #pragma unroll
        for (int d = 32; d >= 1; d >>= 1) m = fmaxf(m, __shfl_xor(m, d));
        float se = 0.f, sw = 0.f;
        for (int o = lane; o < 512; o += 64) {
            float e = __expf(s_alog[r][o] - m);
            se += e; sw += e * s_obs[r][o];
        }
        #pragma unroll
        for (int d = 32; d >= 1; d >>= 1) { se += __shfl_xor(se, d); sw += __shfl_xor(sw, d); }
        if (lane == 0) s_x[r] = sw / se;
    }
    __syncthreads();

    // GRU finish: hnew = (1-z)*n + z*hp  (gates already have b_hh)
    #pragma unroll
    for (int q = 0; q < 4; ++q) {
        int e = tid + q * 512;              // 0..2047
        int r = e >> 8, j = e & 255;
        int grow = row0 + r;
        float g0 = gates[(size_t)grow * 768 + j];
        float g1 = gates[(size_t)grow * 768 + 256 + j];
        float g2 = gates[(size_t)grow * 768 + 512 + j];
        float hp = hmem[(size_t)grow * 256 + j];
        float x  = s_x[r];
        float rg = fast_sig(fmaf(x, W_ih[j], b_ih[j]) + g0);
        float zg = fast_sig(fmaf(x, W_ih[256 + j], b_ih[256 + j]) + g1);
        float ng = fast_tanh(fmaf(x, W_ih[512 + j], b_ih[512 + j]) + rg * g2);
        hnew[(size_t)grow * 256 + j] = (1.0f - zg) * ng + zg * hp;
    }
}

// ---- out2 = relu([feat | hnew] @ W2T + b2); same core as gemm_bcast ----
__global__ __launch_bounds__(256) void gemm_out2(
    const float* __restrict__ b2, float* __restrict__ ws)
{
    __shared__ float s_act[16 * 768];
    float4* P = (float4*)s_act;

    const int bid = blockIdx.x;
    const int rowb = bid >> 2, colb = bid & 3;
    const int m0 = rowb * 16;
    const float* feat = ws + FEAT_OFF;
    const float* hnew = ws + HNEW_OFF;
    const float4* Bt4 = (const float4*)(ws + W2T_OFF);   // [768][128] f4
    float* C = ws + OUT2_OFF;

    for (int i = threadIdx.x; i < 16 * 192; i += 256) {
        int r = i / 192, kq = i - r * 192;
        float4 v = (kq < 128)
            ? *(const float4*)&feat[(size_t)(m0 + r) * 512 + kq * 4]
            : *(const float4*)&hnew[(size_t)(m0 + r) * 256 + (kq - 128) * 4];
        *(float4*)&s_act[r * 768 + kq * 4] = v;
    }
    __syncthreads();

    const int lane = threadIdx.x & 63, wv = threadIdx.x >> 6;
    const int kq2 = lane & 1, c4l = lane >> 1;
    const int kslice = 96;
    const int k0 = (wv * 2 + kq2) * kslice;
    const int cq = colb * 32 + c4l;

    float4 acc[16];
    #pragma unroll
    for (int r = 0; r < 16; ++r) acc[r] = make_float4(0.f, 0.f, 0.f, 0.f);

    #pragma unroll 2
    for (int kk = k0; kk < k0 + kslice; kk += 4) {
        float4 w0 = Bt4[(kk + 0) * 128 + cq];
        float4 w1 = Bt4[(kk + 1) * 128 + cq];
        float4 w2 = Bt4[(kk + 2) * 128 + cq];
        float4 w3 = Bt4[(kk + 3) * 128 + cq];
        #pragma unroll
        for (int r = 0; r < 16; ++r) {
            float4 o = *(const float4*)&s_act[r * 768 + kk];
            fma4(acc[r], o.x, w0); fma4(acc[r], o.y, w1);
            fma4(acc[r], o.z, w2); fma4(acc[r], o.w, w3);
        }
    }
    #pragma unroll
    for (int r = 0; r < 16; ++r) {
        acc[r].x += __shfl_xor(acc[r].x, 1);
        acc[r].y += __shfl_xor(acc[r].y, 1);
        acc[r].z += __shfl_xor(acc[r].z, 1);
        acc[r].w += __shfl_xor(acc[r].w, 1);
    }
    __syncthreads();
    if (kq2 == 0) {
        #pragma unroll
        for (int r = 0; r < 16; ++r) P[(r * 4 + wv) * 32 + c4l] = acc[r];
    }
    __syncthreads();
    const float4* bias4 = (const float4*)b2;
    for (int s = threadIdx.x; s < 512; s += 256) {
        int r = s >> 5, c = s & 31;
        float4 p0 = P[(r * 4 + 0) * 32 + c];
        float4 p1 = P[(r * 4 + 1) * 32 + c];
        float4 p2 = P[(r * 4 + 2) * 32 + c];
        float4 p3 = P[(r * 4 + 3) * 32 + c];
        float4 bb = bias4[colb * 32 + c];
        float4 v;
        v.x = fmaxf(p0.x + p1.x + p2.x + p3.x + bb.x, 0.f);
        v.y = fmaxf(p0.y + p1.y + p2.y + p3.y + bb.y, 0.f);
        v.z = fmaxf(p0.z + p1.z + p2.z + p3.z + bb.z, 0.f);
        v.w = fmaxf(p0.w + p1.w + p2.w + p3.w + bb.w, 0.f);
        *(float4*)&C[(size_t)(m0 + r) * 512 + (colb * 32 + c) * 4] = v;
    }
}

// ---- heads + categorical sampling; wave per row, 8 rows/block ----
__global__ __launch_bounds__(512) void heads_kernel(
    const float* __restrict__ Wact,  const float* __restrict__ bact,
    const float* __restrict__ Wcrit, const float* __restrict__ bcrit,
    const float* __restrict__ ws,    float* __restrict__ out)
{
    const int wv = threadIdx.x >> 6, lane = threadIdx.x & 63;
    const int grow = blockIdx.x * 8 + wv;
    const float* o2 = ws + OUT2_OFF;

    float4 x0 = *(const float4*)&o2[(size_t)grow * 512 + lane * 8];
    float4 x1 = *(const float4*)&o2[(size_t)grow * 512 + lane * 8 + 4];

    float la[ACT];
    #pragma unroll
    for (int a = 0; a < ACT; ++a) {
        const float4* wa4 = (const float4*)&Wact[a * HS2 + lane * 8];
        float4 w0 = wa4[0], w1 = wa4[1];
        float p = x0.x * w0.x + x0.y * w0.y + x0.z * w0.z + x0.w * w0.w
                + x1.x * w1.x + x1.y * w1.y + x1.z * w1.z + x1.w * w1.w;
        #pragma unroll
        for (int d = 32; d >= 1; d >>= 1) p += __shfl_xor(p, d);
        la[a] = p + bact[a];
    }
    const float4* wc4 = (const float4*)&Wcrit[lane * 8];
    float4 w0 = wc4[0], w1 = wc4[1];
    float pv = x0.x * w0.x + x0.y * w0.y + x0.z * w0.z + x0.w * w0.w
             + x1.x * w1.x + x1.y * w1.y + x1.z * w1.z + x1.w * w1.w;
    #pragma unroll
    for (int d = 32; d >= 1; d >>= 1) pv += __shfl_xor(pv, d);

    float g = (lane < ACT) ? gumbel_ra(grow, lane) : 0.0f;
    float best = -1e30f; int amax = 0;
    float mx = -1e30f;
    #pragma unroll
    for (int a = 0; a < ACT; ++a) {
        float g_ = __shfl(g, a);
        float y = la[a] + g_;
        if (y > best) { best = y; amax = a; }   // first-max tie-break
        mx = fmaxf(mx, la[a]);
    }
    float se = 0.f;
    #pragma unroll
    for (int a = 0; a < ACT; ++a) se += __expf(la[a] - mx);
    float lse = mx + logf(se);
    float lp = la[amax] - lse;
    if (lane == 0) {
        out[grow]          = (float)amax;
        out[NW + grow]     = pv + bcrit[0];
        out[2 * NW + grow] = lp;
    }
}

extern "C" void kernel_launch(void* const* d_in, const int* in_sizes, int n_in,
                              void* d_out, int out_size, void* d_ws, size_t ws_size,
                              hipStream_t stream) {
    const float* obs   = (const float*)d_in[0];
    const float* hmem  = (const float*)d_in[1];
    const float* W1    = (const float*)d_in[2];
    const float* b1    = (const float*)d_in[3];
    const float* Wc    = (const float*)d_in[4];
    const float* bc    = (const float*)d_in[5];
    const float* Wa    = (const float*)d_in[6];
    const float* ba    = (const float*)d_in[7];
    const float* W_ih  = (const float*)d_in[8];
    const float* b_ih  = (const float*)d_in[9];
    const float* W_hh  = (const float*)d_in[10];
    const float* b_hh  = (const float*)d_in[11];
    const float* W2    = (const float*)d_in[12];
    const float* b2    = (const float*)d_in[13];
    const float* Wact  = (const float*)d_in[14];
    const float* bact  = (const float*)d_in[15];
    const float* Wcrit = (const float*)d_in[16];
    const float* bcrit = (const float*)d_in[17];
    float* ws = (float*)d_ws;

    transpose_weights<<<864, 256, 0, stream>>>(W1, Wc, W_hh, W2, ws);
    gemm_bcast<<<1408, 256, 0, stream>>>(obs, hmem, b1, bc, b_hh, ws);
    attn_gru_kernel<<<256, 512, 0, stream>>>(obs, hmem, Wc, Wa, ba, W_ih, b_ih, ws);
    gemm_out2<<<512, 256, 0, stream>>>(b2, ws);
    heads_kernel<<<256, 512, 0, stream>>>(Wact, bact, Wcrit, bcrit, ws, (float*)d_out);
}